// Round 4
// baseline (332.738 us; speedup 1.0000x reference)
//
#include <hip/hip_runtime.h>

#define HD  64
#define FIN 128

// ---- workspace float offsets ----
#define WS_W1H   0        // [64][128] bf16 hi  (B-operand layout: [col][k])
#define WS_W1L   4096     // [64][128] bf16 lo
#define WS_MALL  8192     // [208][64] bf16: rows 0-63 K, 64-127 Q, 128-191 VW,
                          //   192 skip-vec, 193-207 zero
#define WS_BK    14848    // [64] f32  bk + b2@WkT
#define WS_BQ    14912
#define WS_BVW   14976
#define WS_BASE  15040    // scalar: bsc + b_gate.Wsc + b2.wsk
#define WS_CNT   15104    // int[32]  bucket counts
#define WS_BOFF  15136    // int[34]  bucket offsets
#define WS_CUR   15172    // int[32]  scatter cursors
#define WS_K     15360    // [N][64B] u8 k   (16 floats/node)
// QV = K + N*16 floats : [N][192B] q u8[64] | vw bf16[64] (48 floats/node)
// EBUF = QV + N*48 floats : u32[E] packed dst|src_local<<17

#define BSHIFT 12         // 4096 nodes per src-bucket

// sigmoid quintic on clamped domain x in [-2,2], encoded s = 64*x:
#define C1f  3.9026344e-3f
#define C3f  (-7.67612e-8f)
#define C5f  1.2236660e-12f

typedef __attribute__((ext_vector_type(8))) short short8;
typedef __attribute__((ext_vector_type(4))) float f32x4;

__device__ __forceinline__ unsigned bf16rne(float f) {
    unsigned u = __float_as_uint(f);
    unsigned r = ((u >> 16) & 1u) + 0x7fffu;
    return (u + r) >> 16;
}
__device__ __forceinline__ float blo(unsigned u) { return __uint_as_float(u << 16); }
__device__ __forceinline__ float bhi(unsigned u) { return __uint_as_float(u & 0xffff0000u); }

// 4 features: k,q u8 quads + 4 bf16 vw in (va,vb)
__device__ __forceinline__ float grp4(unsigned ku, unsigned qu, unsigned va,
                                      unsigned vb, float p) {
    #pragma unroll
    for (int i = 0; i < 4; ++i) {
        float kf = (float)((ku >> (8 * i)) & 255u);
        float qf = (float)((qu >> (8 * i)) & 255u);
        unsigned vu = (i < 2) ? va : vb;
        float vf = (i & 1) ? bhi(vu) : blo(vu);
        float xx = kf + qf;
        xx = fminf(fmaxf(xx, 128.f), 384.f);
        float sv = xx - 256.f;
        float z = sv * sv;
        float w = fmaf(z, C5f, C3f);
        w = fmaf(z, w, C1f);
        p = fmaf(vf * sv, w, p);
        p = fmaf(vf, 0.5f, p);
    }
    return p;
}

// ---------------------------------------------------------------------------
// Prep (15 blocks): b0 W1 hi/lo bf16 split; b1-12 folds -> Mall bf16;
// b13 skip fold; b14 zero partition counters.
// ---------------------------------------------------------------------------
__global__ void gnn_prep(const float* __restrict__ W1, const float* __restrict__ W2,
                         const float* __restrict__ b2,
                         const float* __restrict__ Wk, const float* __restrict__ bk,
                         const float* __restrict__ Wq, const float* __restrict__ bq,
                         const float* __restrict__ Wv, const float* __restrict__ bv,
                         const float* __restrict__ Wsm, const float* __restrict__ Wsc,
                         const float* __restrict__ bgate, const float* __restrict__ bsc,
                         float* __restrict__ ws) {
    __shared__ float w2s[4096];
    __shared__ float wxsT[65 * 64];    // [c][o], stride 65
    int b = blockIdx.x, t = threadIdx.x;
    unsigned short* w1h  = (unsigned short*)(ws + WS_W1H);
    unsigned short* w1l  = (unsigned short*)(ws + WS_W1L);
    unsigned short* mall = (unsigned short*)(ws + WS_MALL);
    if (b == 0) {                                   // W1 split (native [o][c] layout)
        for (int idx = t; idx < HD * FIN; idx += blockDim.x) {
            float v = W1[idx];
            unsigned u = __float_as_uint(v);
            w1h[idx] = (unsigned short)(u >> 16);             // truncated hi
            float rem = v - __uint_as_float(u & 0xffff0000u);
            w1l[idx] = (unsigned short)bf16rne(rem);          // rne lo
        }
    } else if (b <= 12) {
        int m = (b - 1) >> 2, qtr = (b - 1) & 3;
        const float* Wx = (m == 0) ? Wk : (m == 1) ? Wq : Wv;
        const float* bx = (m == 0) ? bk : (m == 1) ? bq : bv;
        int boffw = (m == 0) ? WS_BK : (m == 1) ? WS_BQ : WS_BVW;
        for (int i = t * 4; i < 4096; i += 1024)
            *(float4*)&w2s[i] = *(const float4*)&W2[i];
        for (int idx = t; idx < 4096; idx += 256) {
            int o = idx >> 6, c = idx & 63;
            wxsT[c * 65 + o] = Wx[idx];
        }
        __syncthreads();
        for (int idx = t; idx < 1024; idx += 256) {
            int a = qtr * 16 + (idx >> 6), o = idx & 63;
            float acc = 0.f;
            for (int c = 0; c < HD; ++c) acc += w2s[c * HD + a] * wxsT[c * 65 + o];
            if (m == 2) acc *= Wsc[o];
            mall[(m * 64 + o) * HD + a] = (unsigned short)bf16rne(acc);
        }
        if (qtr == 0 && t < HD) {
            float acc = bx[t];
            for (int c = 0; c < HD; ++c) acc += b2[c] * wxsT[c * 65 + t];
            if (m == 2) acc *= Wsc[t];
            ws[boffw + t] = acc;
        }
    } else if (b == 13) {                           // skip-path fold
        __shared__ float wsk[HD];
        if (t < HD) {
            float a = 0.f;
            for (int d = 0; d < HD; ++d) a += Wsm[d * HD + t] * Wsc[d];
            wsk[t] = a;
        }
        __syncthreads();
        if (t < HD) {
            float a = 0.f;
            for (int c = 0; c < HD; ++c) a += W2[c * HD + t] * wsk[c];
            mall[192 * HD + t] = (unsigned short)bf16rne(a);
        }
        for (int idx = t; idx < 15 * HD; idx += 256)     // zero rows 193-207
            mall[193 * HD + idx] = 0;
        if (t == 0) {
            float a = bsc[0];
            for (int d = 0; d < HD; ++d) a += bgate[d] * Wsc[d];
            float acc2 = 0.f;
            for (int c = 0; c < HD; ++c) {
                float wk2 = 0.f;
                for (int d = 0; d < HD; ++d) wk2 += Wsm[d * HD + c] * Wsc[d];
                acc2 += b2[c] * wk2;
            }
            ws[WS_BASE] = a + acc2;
        }
    } else {                                        // b==14: zero counters
        if (t < 128) ((int*)(ws + WS_CNT))[t] = 0;
    }
}

// ---------------------------------------------------------------------------
// MFMA node kernel (unchanged math from r3). Epilogue now writes split arrays:
// K[node][64B] u8  and  QV[node][192B] = q u8[64] | vw bf16[64].
// ---------------------------------------------------------------------------
__global__ __launch_bounds__(256, 3) void gnn_node(const float* __restrict__ x,
                                                   const float* __restrict__ b1,
                                                   const float* __restrict__ ws,
                                                   uint4* __restrict__ karr,
                                                   uint4* __restrict__ qv,
                                                   float* __restrict__ score, int N) {
    __shared__ __align__(16) char smem[32768];
    char* XHb = smem;
    char* XLb = smem + 16384;

    int tid = threadIdx.x;
    int l = tid & 63, w = tid >> 6;
    int nbase = blockIdx.x * 64;

    // ---- stage x -> XH/XL (wave-aligned rows, split bf16, swizzled) ----
    #pragma unroll
    for (int it = 0; it < 8; ++it) {
        int idx = it * 64 + l;
        int nl = 16 * w + (idx >> 5);
        int c4 = idx & 31;
        int node = min(nbase + nl, N - 1);
        float4 v = ((const float4*)x)[(size_t)node * 32 + c4];
        unsigned u0 = __float_as_uint(v.x), u1 = __float_as_uint(v.y);
        unsigned u2 = __float_as_uint(v.z), u3 = __float_as_uint(v.w);
        uint2 hx, lx;
        hx.x = (u0 >> 16) | (u1 & 0xffff0000u);
        hx.y = (u2 >> 16) | (u3 & 0xffff0000u);
        float r0 = v.x - __uint_as_float(u0 & 0xffff0000u);
        float r1 = v.y - __uint_as_float(u1 & 0xffff0000u);
        float r2 = v.z - __uint_as_float(u2 & 0xffff0000u);
        float r3 = v.w - __uint_as_float(u3 & 0xffff0000u);
        lx.x = bf16rne(r0) | (bf16rne(r1) << 16);
        lx.y = bf16rne(r2) | (bf16rne(r3) << 16);
        int bo = (nl * 256 + c4 * 8) ^ ((nl & 7) << 4);
        *(uint2*)(XHb + bo) = hx;
        *(uint2*)(XLb + bo) = lx;
    }
    __syncthreads();

    int rl = l & 15, kb = l >> 4;
    int rowA = 16 * w + rl;
    int swzA = (rowA & 7) << 4;

    // ---- phase 1: 3-way split bf16 MFMA, K=128 ----
    const unsigned short* w1h = (const unsigned short*)(ws + WS_W1H);
    const unsigned short* w1l = (const unsigned short*)(ws + WS_W1L);
    f32x4 acc1[4];
    #pragma unroll
    for (int t = 0; t < 4; ++t) {
        float bv = b1[t * 16 + rl];
        acc1[t] = (f32x4){bv, bv, bv, bv};
    }
    #pragma unroll
    for (int s = 0; s < 4; ++s) {
        int abyte = (rowA * 256 + s * 64 + kb * 16) ^ swzA;
        short8 ah = *(const short8*)(XHb + abyte);
        short8 al = *(const short8*)(XLb + abyte);
        int koff = s * 32 + kb * 8;
        #pragma unroll
        for (int t = 0; t < 4; ++t) {
            int col = t * 16 + rl;
            short8 bh = *(const short8*)&w1h[col * FIN + koff];
            short8 bl = *(const short8*)&w1l[col * FIN + koff];
            acc1[t] = __builtin_amdgcn_mfma_f32_16x16x32_bf16(ah, bh, acc1[t], 0, 0, 0);
            acc1[t] = __builtin_amdgcn_mfma_f32_16x16x32_bf16(al, bh, acc1[t], 0, 0, 0);
            acc1[t] = __builtin_amdgcn_mfma_f32_16x16x32_bf16(ah, bl, acc1[t], 0, 0, 0);
        }
    }
    __syncthreads();

    // ---- relu + bf16, write H [64][64] swizzled (aliases XH) ----
    int r0w = (l >> 4) * 4;
    #pragma unroll
    for (int t = 0; t < 4; ++t) {
        int col = t * 16 + rl;
        #pragma unroll
        for (int r = 0; r < 4; ++r) {
            int row = 16 * w + r0w + r;
            float v = fmaxf(acc1[t][r], 0.f);
            int hb = (row * 128 + col * 2) ^ ((row & 7) << 4);
            *(unsigned short*)(smem + hb) = (unsigned short)bf16rne(v);
        }
    }
    __syncthreads();

    // ---- phase 2: [K|Q|VW|skip] = H @ Mall, K=64, 13 N-tiles ----
    const unsigned short* mall = (const unsigned short*)(ws + WS_MALL);
    const float* bK = ws + WS_BK;
    const float* bQ = ws + WS_BQ;
    const float* bV = ws + WS_BVW;
    float base = ws[WS_BASE];
    f32x4 acc2[13];
    #pragma unroll
    for (int t = 0; t < 4; ++t) {
        float v = bK[t * 16 + rl];
        acc2[t] = (f32x4){v, v, v, v};
    }
    #pragma unroll
    for (int t = 0; t < 4; ++t) {
        float v = bQ[t * 16 + rl];
        acc2[4 + t] = (f32x4){v, v, v, v};
    }
    #pragma unroll
    for (int t = 0; t < 4; ++t) {
        float v = bV[t * 16 + rl];
        acc2[8 + t] = (f32x4){v, v, v, v};
    }
    acc2[12] = (f32x4){0.f, 0.f, 0.f, 0.f};

    #pragma unroll
    for (int s = 0; s < 2; ++s) {
        int abyte = (rowA * 128 + (s * 32 + kb * 8) * 2) ^ swzA;
        short8 a = *(const short8*)(smem + abyte);
        int koff = s * 32 + kb * 8;
        #pragma unroll
        for (int t = 0; t < 13; ++t) {
            short8 b = *(const short8*)&mall[(t * 16 + rl) * HD + koff];
            acc2[t] = __builtin_amdgcn_mfma_f32_16x16x32_bf16(a, b, acc2[t], 0, 0, 0);
        }
    }

    // ---- epilogue: quantize to LDS staging, then coalesced copy to K / QV ----
    char* Ku = smem + 16384;
    char* Qu = smem + 20480;
    char* VW = smem + 24576;
    #pragma unroll
    for (int t = 0; t < 4; ++t) {
        int col = t * 16 + rl;
        #pragma unroll
        for (int r = 0; r < 4; ++r) {
            int row = 16 * w + r0w + r;
            int ek = min(max(__float2int_rn(fmaf(acc2[t][r],     64.f, 128.f)), 0), 255);
            int eq = min(max(__float2int_rn(fmaf(acc2[4 + t][r], 64.f, 128.f)), 0), 255);
            Ku[row * 64 + col] = (char)ek;
            Qu[row * 64 + col] = (char)eq;
            *(unsigned short*)(VW + row * 128 + col * 2) =
                (unsigned short)bf16rne(acc2[8 + t][r]);
        }
    }
    if (rl == 0) {
        #pragma unroll
        for (int r = 0; r < 4; ++r) {
            int node = nbase + 16 * w + r0w + r;
            if (node < N) score[node] = base + acc2[12][r];
        }
    }
    __syncthreads();

    {   // K: 64 nodes x 4 uint4
        int n = tid >> 2, p = tid & 3;
        int node = nbase + n;
        if (node < N)
            karr[(size_t)node * 4 + p] = *(const uint4*)(Ku + n * 64 + p * 16);
    }
    #pragma unroll
    for (int it = 0; it < 3; ++it) {               // QV: 64 nodes x 12 uint4
        int n = tid >> 2, p = (tid & 3) + it * 4;
        int node = nbase + n;
        const char* srcp = (p < 4) ? (Qu + n * 64 + p * 16)
                                   : (VW + n * 128 + (p - 4) * 16);
        if (node < N) qv[(size_t)node * 12 + p] = *(const uint4*)srcp;
    }
}

// ---------------------------------------------------------------------------
// Partition pass 1: per-block LDS histogram of src buckets.
// ---------------------------------------------------------------------------
__global__ __launch_bounds__(256) void gnn_hist(const int* __restrict__ ei,
                                                int* __restrict__ cnt, int E) {
    __shared__ int lc[32];
    int t = threadIdx.x;
    if (t < 32) lc[t] = 0;
    __syncthreads();
    for (int e = blockIdx.x * 256 + t; e < E; e += gridDim.x * 256)
        atomicAdd(&lc[ei[e] >> BSHIFT], 1);
    __syncthreads();
    if (t < 32 && lc[t]) atomicAdd(&cnt[t], lc[t]);
}

// ---------------------------------------------------------------------------
// Partition pass 2: serial exclusive scan (32 entries) + cursor init.
// ---------------------------------------------------------------------------
__global__ void gnn_scan(const int* __restrict__ cnt, int* __restrict__ boff,
                         int* __restrict__ cur) {
    if (threadIdx.x == 0) {
        int s = 0;
        for (int b = 0; b < 32; ++b) { boff[b] = s; cur[b] = s; s += cnt[b]; }
        boff[32] = s;
    }
}

// ---------------------------------------------------------------------------
// Partition pass 3: block multisplit scatter. 1024 edges/block, LDS counts,
// one global reservation per bucket per block, LDS-cursor ordered writes.
// Packs edge as dst | (src&4095)<<17.
// ---------------------------------------------------------------------------
__global__ __launch_bounds__(256) void gnn_scatter(const int* __restrict__ ei,
                                                   int* __restrict__ cur,
                                                   unsigned* __restrict__ ebuf, int E) {
    __shared__ int lc[32], gb[32], lcur[32];
    int t = threadIdx.x;
    int base = blockIdx.x * 1024;
    if (t < 32) lc[t] = 0;
    __syncthreads();
    int myb[4]; unsigned mypk[4];
    #pragma unroll
    for (int i = 0; i < 4; ++i) {
        int e = base + i * 256 + t;
        myb[i] = -1;
        if (e < E) {
            int src = ei[e], dst = ei[E + e];
            myb[i] = src >> BSHIFT;
            mypk[i] = (unsigned)dst | ((unsigned)(src & 4095) << 17);
            atomicAdd(&lc[myb[i]], 1);
        }
    }
    __syncthreads();
    if (t < 32) {
        gb[t] = lc[t] ? atomicAdd(&cur[t], lc[t]) : 0;
        lcur[t] = 0;
    }
    __syncthreads();
    #pragma unroll
    for (int i = 0; i < 4; ++i) {
        if (myb[i] >= 0) {
            int r = atomicAdd(&lcur[myb[i]], 1);
            ebuf[gb[myb[i]] + r] = mypk[i];
        }
    }
}

// ---------------------------------------------------------------------------
// Edge pass, src-bucketed + XCD-pinned: blocks with bid&7==x process buckets
// x, x+8, x+16, x+24 -> each 786KB QV window is L2-resident on one XCD.
// 4 lanes/edge; k gathered from compact K array; 1 atomic/edge.
// ---------------------------------------------------------------------------
__global__ __launch_bounds__(256) void gnn_edge(const unsigned* __restrict__ ebuf,
                                                const int* __restrict__ boff,
                                                const uint4* __restrict__ karr,
                                                const uint4* __restrict__ qv,
                                                float* __restrict__ score,
                                                int nb, int cpb) {
    int bid = blockIdx.x;
    int x = bid & 7, ci = bid >> 3;
    int t = threadIdx.x;
    int q = t >> 2, f = t & 3;
    for (int sb = 0; sb < 4; ++sb) {
        int b = x + 8 * sb;
        if (b >= nb) break;
        int eend = boff[b + 1];
        for (int c = ci; ; c += cpb) {             // stride-loop: overflow-safe
            int e0 = boff[b] + c * 64;
            if (e0 >= eend) break;
            int ge = e0 + q;
            if (ge < eend) {
                unsigned pk = ebuf[ge];
                int dst = (int)(pk & 0x1FFFFu);
                int src = (b << BSHIFT) + (int)(pk >> 17);
                uint4 ku = karr[(size_t)dst * 4 + f];
                uint4 qu = qv[(size_t)src * 12 + f];
                uint4 va = qv[(size_t)src * 12 + 4 + 2 * f];
                uint4 vb = qv[(size_t)src * 12 + 5 + 2 * f];
                float p = 0.f;
                p = grp4(ku.x, qu.x, va.x, va.y, p);
                p = grp4(ku.y, qu.y, va.z, va.w, p);
                p = grp4(ku.z, qu.z, vb.x, vb.y, p);
                p = grp4(ku.w, qu.w, vb.z, vb.w, p);
                p += __shfl_down(p, 2, 4);
                p += __shfl_down(p, 1, 4);
                if (f == 0) atomicAdd(&score[dst], p);
            }
        }
    }
}

// ---------------------------------------------------------------------------
extern "C" void kernel_launch(void* const* d_in, const int* in_sizes, int n_in,
                              void* d_out, int out_size, void* d_ws, size_t ws_size,
                              hipStream_t stream) {
    const float* x    = (const float*)d_in[0];
    const int*   ei   = (const int*)d_in[1];
    const float* W1   = (const float*)d_in[2];
    const float* b1   = (const float*)d_in[3];
    const float* W2   = (const float*)d_in[4];
    const float* b2   = (const float*)d_in[5];
    const float* Wk   = (const float*)d_in[6];
    const float* bk   = (const float*)d_in[7];
    const float* Wq   = (const float*)d_in[8];
    const float* bq   = (const float*)d_in[9];
    const float* Wv   = (const float*)d_in[10];
    const float* bv   = (const float*)d_in[11];
    const float* Wsm  = (const float*)d_in[12];
    const float* bgat = (const float*)d_in[13];
    const float* Wsc  = (const float*)d_in[14];
    const float* bsc  = (const float*)d_in[15];

    int N = in_sizes[0] / FIN;
    int E = in_sizes[1] / 2;

    float* ws    = (float*)d_ws;
    int*   cnt   = (int*)(ws + WS_CNT);
    int*   boff  = (int*)(ws + WS_BOFF);
    int*   cur   = (int*)(ws + WS_CUR);
    float* karr  = ws + WS_K;                     // N*16 floats (64B/node)
    float* qvarr = karr + (size_t)N * 16;         // N*48 floats (192B/node)
    unsigned* ebuf = (unsigned*)(qvarr + (size_t)N * 48);
    float* score = (float*)d_out;

    int NB = (N + 63) / 64;
    int nb = (N + (1 << BSHIFT) - 1) >> BSHIFT;   // 25 buckets
    // chunk capacity per bucket (stride-loop covers any overflow)
    long long mean = ((long long)E << BSHIFT) / N;
    int cpb = (int)(mean * 108 / 100 / 64) + 2;

    gnn_prep<<<15, 256, 0, stream>>>(W1, W2, b2, Wk, bk, Wq, bq, Wv, bv,
                                     Wsm, Wsc, bgat, bsc, ws);
    gnn_node<<<NB, 256, 0, stream>>>(x, b1, ws, (uint4*)karr, (uint4*)qvarr,
                                     score, N);
    gnn_hist<<<1024, 256, 0, stream>>>(ei, cnt, E);
    gnn_scan<<<1, 64, 0, stream>>>(cnt, boff, cur);
    gnn_scatter<<<(E + 1023) / 1024, 256, 0, stream>>>(ei, cur, ebuf, E);
    gnn_edge<<<8 * cpb, 256, 0, stream>>>(ebuf, boff, (const uint4*)karr,
                                          (const uint4*)qvarr, score, nb, cpb);
}